// Round 10
// baseline (116.979 us; speedup 1.0000x reference)
//
#include <hip/hip_runtime.h>
#include <hip/hip_bf16.h>
#include <math.h>

#define W_  160
#define H_  128
#define HW  20480
#define D_  48
#define C_  32
#define NV  4    // source views (views 1..4)
#define DB  8    // depth-block in k_warp
#define NCHK 3   // depth chunks per pixel (16 depths per wave)

// conv/softmax tile
#define TX  16
#define TY  4
#define TXH 18
#define TYH 6
#define NCOL (TXH*TYH)   // 108

// ---------------- cross-lane helpers ----------------
template<int CTRL>
__device__ __forceinline__ float dpp_add(float s) {
  int t = __builtin_amdgcn_update_dpp(0, __float_as_int(s), CTRL, 0xF, 0xF, true);
  return s + __int_as_float(t);
}
__device__ __forceinline__ float swz_add4(float s) {
  int t = __builtin_amdgcn_ds_swizzle(__float_as_int(s), 0x101F);  // xor 4
  return s + __int_as_float(t);
}

// monotone float<->uint ordering (for atomic max)
__device__ __forceinline__ unsigned ordf(float f) {
  unsigned b = __float_as_uint(f);
  return b ^ (((int)b >> 31) | 0x80000000u);
}
__device__ __forceinline__ float deordf(unsigned u) {
  unsigned b = (u & 0x80000000u) ? (u ^ 0x80000000u) : ~u;
  return __uint_as_float(b);
}

// ---------------- projection helpers ----------------
__device__ __forceinline__ void fuse_proj(const float* pm, float* P) {
  const float* E = pm;
  const float* K = pm + 16;
  for (int r = 0; r < 3; ++r)
    for (int c = 0; c < 4; ++c)
      P[r*4+c] = K[r*4+0]*E[0*4+c] + K[r*4+1]*E[1*4+c] + K[r*4+2]*E[2*4+c];
  for (int c = 0; c < 4; ++c) P[12+c] = E[12+c];
}

__device__ void invert4(const float* m, float* invOut) {
  float inv[16];
  inv[0]  =  m[5]*m[10]*m[15] - m[5]*m[11]*m[14] - m[9]*m[6]*m[15] + m[9]*m[7]*m[14] + m[13]*m[6]*m[11] - m[13]*m[7]*m[10];
  inv[4]  = -m[4]*m[10]*m[15] + m[4]*m[11]*m[14] + m[8]*m[6]*m[15] - m[8]*m[7]*m[14] - m[12]*m[6]*m[11] + m[12]*m[7]*m[10];
  inv[8]  =  m[4]*m[9]*m[15]  - m[4]*m[11]*m[13] - m[8]*m[5]*m[15] + m[8]*m[7]*m[13] + m[12]*m[5]*m[11] - m[12]*m[7]*m[9];
  inv[12] = -m[4]*m[9]*m[14]  + m[4]*m[10]*m[13] + m[8]*m[5]*m[14] - m[8]*m[6]*m[13] - m[12]*m[5]*m[10] + m[12]*m[6]*m[9];
  inv[1]  = -m[1]*m[10]*m[15] + m[1]*m[11]*m[14] + m[9]*m[2]*m[15] - m[9]*m[3]*m[14] - m[13]*m[2]*m[11] + m[13]*m[3]*m[10];
  inv[5]  =  m[0]*m[10]*m[15] - m[0]*m[11]*m[14] - m[8]*m[2]*m[15] + m[8]*m[3]*m[14] + m[12]*m[2]*m[11] - m[12]*m[3]*m[10];
  inv[9]  = -m[0]*m[9]*m[15]  + m[0]*m[11]*m[13] + m[8]*m[1]*m[15] - m[8]*m[3]*m[13] - m[12]*m[1]*m[11] + m[12]*m[3]*m[9];
  inv[13] =  m[0]*m[9]*m[14]  - m[0]*m[10]*m[13] - m[8]*m[1]*m[14] + m[8]*m[2]*m[13] + m[12]*m[1]*m[10] - m[12]*m[2]*m[9];
  inv[2]  =  m[1]*m[6]*m[15]  - m[1]*m[7]*m[14]  - m[5]*m[2]*m[15] + m[5]*m[3]*m[14] + m[13]*m[2]*m[7]  - m[13]*m[3]*m[6];
  inv[6]  = -m[0]*m[6]*m[15]  + m[0]*m[7]*m[14]  + m[4]*m[2]*m[15] - m[4]*m[3]*m[14] - m[12]*m[2]*m[7]  + m[12]*m[3]*m[6];
  inv[10] =  m[0]*m[5]*m[15]  - m[0]*m[7]*m[13]  - m[4]*m[1]*m[15] + m[4]*m[3]*m[13] + m[12]*m[1]*m[7]  - m[12]*m[3]*m[5];
  inv[14] = -m[0]*m[5]*m[14]  + m[0]*m[6]*m[13]  + m[4]*m[1]*m[14] - m[4]*m[2]*m[13] - m[12]*m[1]*m[6]  + m[12]*m[2]*m[5];
  inv[3]  = -m[1]*m[6]*m[11]  + m[1]*m[7]*m[10]  + m[5]*m[2]*m[11] - m[5]*m[3]*m[10] - m[9]*m[2]*m[7]   + m[9]*m[3]*m[6];
  inv[7]  =  m[0]*m[6]*m[11]  - m[0]*m[7]*m[10]  - m[4]*m[2]*m[11] + m[4]*m[3]*m[10] + m[8]*m[2]*m[7]   - m[8]*m[3]*m[6];
  inv[11] = -m[0]*m[5]*m[11]  + m[0]*m[7]*m[9]   + m[4]*m[1]*m[11] - m[4]*m[3]*m[9]  - m[8]*m[1]*m[7]   + m[8]*m[3]*m[5];
  inv[15] =  m[0]*m[5]*m[10]  - m[0]*m[6]*m[9]   - m[4]*m[1]*m[10] + m[4]*m[2]*m[9]  + m[8]*m[1]*m[6]   - m[8]*m[2]*m[5];
  float det = m[0]*inv[0] + m[1]*inv[4] + m[2]*inv[8] + m[3]*inv[12];
  det = 1.0f / det;
  for (int i = 0; i < 16; i++) invOut[i] = inv[i] * det;
}

// ---------------- prep: transpose + xform + zero pads/accumulators ---------
__global__ void __launch_bounds__(256)
k_prep(const float* __restrict__ feat, const float* __restrict__ pm,
       float* __restrict__ tf, float* __restrict__ xf,
       unsigned* __restrict__ vwu) {
  __shared__ float tile[C_][64+1];
  int v  = blockIdx.y;
  int p0 = blockIdx.x * 64;
  int t  = threadIdx.x;

  if (v == 0) vwu[blockIdx.x*256 + t] = 0u;

  int pl = t & 63;
  int cg = t >> 6;            // 0..3
  const float* src = feat + (size_t)v*C_*HW + p0 + pl;
  #pragma unroll
  for (int k = 0; k < 8; ++k) {
    int c = cg*8 + k;
    tile[c][pl] = src[(size_t)c*HW];
  }
  __syncthreads();

  int pp = t >> 2;            // pixel 0..63
  int co = (t & 3) * 8;       // channel offset
  float4 a, b;
  a.x = tile[co+0][pp]; a.y = tile[co+1][pp]; a.z = tile[co+2][pp]; a.w = tile[co+3][pp];
  b.x = tile[co+4][pp]; b.y = tile[co+5][pp]; b.z = tile[co+6][pp]; b.w = tile[co+7][pp];
  float* dst = tf + ((size_t)v*HW + p0 + pp)*C_ + co;
  *(float4*)dst = a;
  *(float4*)(dst+4) = b;

  if (blockIdx.x == 0 && v == 0) {
    if (t < 64) tf[(size_t)5*HW*C_ + t] = 0.0f;   // zero pad (invalid corners)
    if (t == 0) {
      float Pr[16], Pinv[16], Ps[16], M[16];
      fuse_proj(pm, Pr);
      invert4(Pr, Pinv);
      for (int vv = 1; vv <= NV; ++vv) {
        fuse_proj(pm + vv*32, Ps);
        for (int r = 0; r < 4; ++r)
          for (int c = 0; c < 4; ++c) {
            float acc = 0.f;
            for (int k = 0; k < 4; ++k) acc += Ps[r*4+k]*Pinv[k*4+c];
            M[r*4+c] = acc;
          }
        float* o = xf + (vv-1)*12;
        o[0]=M[0];  o[1]=M[1];  o[2]=M[2];
        o[3]=M[4];  o[4]=M[5];  o[5]=M[6];
        o[6]=M[8];  o[7]=M[9];  o[8]=M[10];
        o[9]=M[3];  o[10]=M[7]; o[11]=M[11];
      }
    }
  }
}

// ---------------- main warp + similarity kernel ----------------
// Wave = 8 pixels x 8 slots; each wave owns 16 depths (3 waves per (v,pixel)).
// Per 8-depth block:
//   phase 1: each lane builds the descriptor (4 corner byte offsets + 4
//            bilinear weights, shared exact 1/Z) for ONE (pixel,depth) item,
//            stages it to LDS (xor-swizzled, bank-uniform).
//   phase 2: straight-line, branch-free, fully unrolled: per depth 2 b128
//            LDS reads + 4 coalesced float4 corner loads + 16 FMA + weighted
//            sum + DPP/swizzle butterfly. Every depth independent -> deep
//            load pipelining; TLP from 7680 blocks covers L1 latency.
__global__ void __launch_bounds__(256)
k_warp(const float* __restrict__ tf, const float* __restrict__ dv,
       const float* __restrict__ xf, float* __restrict__ sim_all) {
  __shared__ int4   dso[4][64];
  __shared__ float4 dsw[4][64];

  int lane = threadIdx.x & 63;
  int wv = threadIdx.x >> 6;
  int ch = lane & 7;              // channel chunk (phase 2) / depth slot (phase 1)
  int pix = (lane >> 3) & 7;      // pixel within group
  int wvg = __builtin_amdgcn_readfirstlane((blockIdx.x*256 + threadIdx.x) >> 6);
  const int PGPV = HW/8;
  int pg = wvg % PGPV;
  int rest = wvg / PGPV;          // (chunk, v)
  int v  = rest & 3;
  int chunk = rest >> 2;          // 0..2
  int p  = pg*8 + pix;

  float xpix = (float)(p % W_);
  float ypix = (float)(p / W_);

  const float* M = xf + v*12;
  float rx = M[0]*xpix + M[1]*ypix + M[2];
  float ry = M[3]*xpix + M[4]*ypix + M[5];
  float rz = M[6]*xpix + M[7]*ypix + M[8];
  float t0 = M[9], t1 = M[10], t2 = M[11];

  // ref fragment, pre-scaled by 1/C (folds the sim normalization)
  float4 rfc = *(const float4*)(tf + (size_t)p*C_ + ch*4);
  rfc.x *= (1.0f/(float)C_); rfc.y *= (1.0f/(float)C_);
  rfc.z *= (1.0f/(float)C_); rfc.w *= (1.0f/(float)C_);

  const char* tfb = (const char*)(tf + (size_t)(v+1)*HW*C_);
  const int chb = ch*16;
  const int ZB = (4-v)*HW*C_*4;   // byte offset (from view base) of zero pad

  float* simv = sim_all + (size_t)v*D_*HW + p;

  #pragma unroll
  for (int bb = 0; bb < 2; ++bb) {
    int b = chunk*2 + bb;
    // ---- phase 1: one descriptor per lane, staged to LDS ----
    int d1 = b*DB + ch;
    float dep = dv[(size_t)d1*HW + p];
    float Z  = rz*dep + t2;
    float zr = 1.0f / Z;                // exact reciprocal, shared by px,py
    float px = (rx*dep + t0) * zr;
    float py = (ry*dep + t1) * zr;
    float x0f = floorf(px), y0f = floorf(py);
    float wx1 = px - x0f;
    float wy1 = py - y0f;
    float wx0 = 1.0f - wx1, wy0 = 1.0f - wy1;
    int x0 = (int)x0f, y0 = (int)y0f;
    int x1 = x0 + 1,   y1 = y0 + 1;
    bool vx0 = ((unsigned)x0 <= (unsigned)(W_-1));
    bool vx1 = ((unsigned)x1 <= (unsigned)(W_-1));
    bool vy0 = ((unsigned)y0 <= (unsigned)(H_-1));
    bool vy1 = ((unsigned)y1 <= (unsigned)(H_-1));
    int cx0 = min(max(x0, 0), W_-1);
    int cx1 = min(max(x1, 0), W_-1);
    int cy0 = min(max(y0, 0), H_-1);
    int cy1 = min(max(y1, 0), H_-1);
    int r0 = cy0*W_, r1 = cy1*W_;
    int o00 = (vx0 && vy0) ? (r0+cx0)*(C_*4) : ZB;
    int o01 = (vx1 && vy0) ? (r0+cx1)*(C_*4) : ZB;
    int o10 = (vx0 && vy1) ? (r1+cx0)*(C_*4) : ZB;
    int o11 = (vx1 && vy1) ? (r1+cx1)*(C_*4) : ZB;

    int key = (ch<<3) | (pix ^ ch);          // bank-uniform for write & read
    dso[wv][key] = make_int4(o00, o01, o10, o11);
    dsw[wv][key] = make_float4(wx0*wy0, wx1*wy0, wx0*wy1, wx1*wy1);

    // ---- phase 2: 8 depths, branch-free, fully unrolled ----
    #pragma unroll
    for (int dd = 0; dd < DB; ++dd) {
      int it = (dd<<3) | (pix ^ dd);
      int4   O  = dso[wv][it];
      float4 Wt = dsw[wv][it];

      float4 a  = *(const float4*)(tfb + (O.x + chb));
      float4 bq = *(const float4*)(tfb + (O.y + chb));
      float4 g  = *(const float4*)(tfb + (O.z + chb));
      float4 e  = *(const float4*)(tfb + (O.w + chb));

      float d00 = a.x*rfc.x  + a.y*rfc.y  + a.z*rfc.z  + a.w*rfc.w;
      float d01 = bq.x*rfc.x + bq.y*rfc.y + bq.z*rfc.z + bq.w*rfc.w;
      float d10 = g.x*rfc.x  + g.y*rfc.y  + g.z*rfc.z  + g.w*rfc.w;
      float d11 = e.x*rfc.x  + e.y*rfc.y  + e.z*rfc.z  + e.w*rfc.w;

      float s = Wt.x*d00 + Wt.y*d01 + Wt.z*d10 + Wt.w*d11;
      s = dpp_add<0xB1>(s);   // xor 1
      s = dpp_add<0x4E>(s);   // xor 2
      s = swz_add4(s);        // xor 4
      if (ch == 0) simv[(size_t)(b*DB + dd)*HW] = s;
    }
  }
}

// ---------------- MLP: 4 depths per thread, atomic-max logit -------------
__global__ void __launch_bounds__(256)
k_mlp(const float* __restrict__ sim_all,
      const float* __restrict__ w0, const float* __restrict__ b0,
      const float* __restrict__ w1, const float* __restrict__ b1,
      const float* __restrict__ w2, const float* __restrict__ b2,
      unsigned* __restrict__ vwu) {
  int idx = blockIdx.x*blockDim.x + threadIdx.x;
  if (idx >= NV*(D_/4)*HW) return;
  int p = idx % HW;
  int t = idx / HW;           // (v, chunk)
  int v = t / (D_/4);
  int c = t % (D_/4);

  const float* sp_ = sim_all + ((size_t)(v*D_ + c*4))*HW + p;
  float sv[4];
  sv[0] = sp_[0];
  sv[1] = sp_[HW];
  sv[2] = sp_[2*HW];
  sv[3] = sp_[3*HW];

  float ymax = -3.0e38f;
  #pragma unroll
  for (int k = 0; k < 4; ++k) {
    float s = sv[k];
    float acc0 = b1[0], acc1 = b1[1], acc2 = b1[2], acc3 = b1[3];
    float acc4 = b1[4], acc5 = b1[5], acc6 = b1[6], acc7 = b1[7];
    #pragma unroll
    for (int o = 0; o < 16; ++o) {
      float h = fmaxf(fmaf(w0[o], s, b0[o]), 0.0f);
      acc0 = fmaf(w1[0*16+o], h, acc0);
      acc1 = fmaf(w1[1*16+o], h, acc1);
      acc2 = fmaf(w1[2*16+o], h, acc2);
      acc3 = fmaf(w1[3*16+o], h, acc3);
      acc4 = fmaf(w1[4*16+o], h, acc4);
      acc5 = fmaf(w1[5*16+o], h, acc5);
      acc6 = fmaf(w1[6*16+o], h, acc6);
      acc7 = fmaf(w1[7*16+o], h, acc7);
    }
    float yv = b2[0];
    yv = fmaf(w2[0], fmaxf(acc0, 0.0f), yv);
    yv = fmaf(w2[1], fmaxf(acc1, 0.0f), yv);
    yv = fmaf(w2[2], fmaxf(acc2, 0.0f), yv);
    yv = fmaf(w2[3], fmaxf(acc3, 0.0f), yv);
    yv = fmaf(w2[4], fmaxf(acc4, 0.0f), yv);
    yv = fmaf(w2[5], fmaxf(acc5, 0.0f), yv);
    yv = fmaf(w2[6], fmaxf(acc6, 0.0f), yv);
    yv = fmaf(w2[7], fmaxf(acc7, 0.0f), yv);
    ymax = fmaxf(ymax, yv);
  }
  atomicMax(&vwu[(size_t)v*HW + p], ordf(ymax));
}

// ---------------- fused: vw-decode + fuse + conv + softmax/argmax ----------
__global__ void __launch_bounds__(256)
k_fct(const float* __restrict__ sim_all, const unsigned* __restrict__ vwu,
      const float* __restrict__ rw, const float* __restrict__ rb,
      const float* __restrict__ dv, float* __restrict__ out) {
  __shared__ float sfus[D_][TYH][TXH+1];
  __shared__ float scost[D_][64];
  __shared__ float svw[NV][NCOL];
  __shared__ float sinvw[NCOL];
  __shared__ int   sgpc[NCOL];

  int tid = threadIdx.x;
  int gx0 = blockIdx.x*TX;
  int gy0 = blockIdx.y*TY;

  // phase A: per-column view weights (decode + sigmoid) / inv wsum / pixel idx
  if (tid < NCOL) {
    int yy = tid / TXH, xx = tid % TXH;
    int gy = gy0 + yy - 1, gx = gx0 + xx - 1;
    bool valid = (gx >= 0) && (gx < W_) && (gy >= 0) && (gy < H_);
    int gp = min(max(gy,0),H_-1)*W_ + min(max(gx,0),W_-1);
    sgpc[tid] = gp;
    float a0 = 1.0f/(1.0f + expf(-deordf(vwu[0*HW+gp])));
    float a1 = 1.0f/(1.0f + expf(-deordf(vwu[1*HW+gp])));
    float a2 = 1.0f/(1.0f + expf(-deordf(vwu[2*HW+gp])));
    float a3 = 1.0f/(1.0f + expf(-deordf(vwu[3*HW+gp])));
    float inv = valid ? 1.0f/(1e-5f + a0+a1+a2+a3) : 0.0f;
    if (!valid) { a0=a1=a2=a3=0.f; }
    svw[0][tid]=a0; svw[1][tid]=a1; svw[2][tid]=a2; svw[3][tid]=a3;
    sinvw[tid] = inv;
  }
  __syncthreads();

  // phase B: fill fused volume tile (invalid columns auto-zero via weights)
  for (int j = tid; j < D_*NCOL; j += 256) {
    int d = j / NCOL, r = j % NCOL;
    int gp = sgpc[r];
    float s0 = sim_all[(size_t)(0*D_+d)*HW + gp];
    float s1 = sim_all[(size_t)(1*D_+d)*HW + gp];
    float s2 = sim_all[(size_t)(2*D_+d)*HW + gp];
    float s3 = sim_all[(size_t)(3*D_+d)*HW + gp];
    float val = (s0*svw[0][r] + s1*svw[1][r] + s2*svw[2][r] + s3*svw[3][r]) * sinvw[r];
    int yy = r / TXH, xx = r % TXH;
    sfus[d][yy][xx] = val;
  }
  __syncthreads();

  // phase C: 3x3x3 conv; thread = (pixel, depth-group of 12)
  {
    int pid = tid & 63;
    int dg  = tid >> 6;
    int px = pid & 15, py = pid >> 4;
    float kw[27];
    #pragma unroll
    for (int i = 0; i < 27; ++i) kw[i] = rw[i];
    float bias = rb[0];

    float pm1[9], p0[9], pp1[9];
    int d0 = dg*12;
    #pragma unroll
    for (int i = 0; i < 9; ++i) {
      int ky = i/3, kx = i%3;
      pm1[i] = (d0 > 0) ? sfus[d0-1][py+ky][px+kx] : 0.0f;
      p0[i]  = sfus[d0][py+ky][px+kx];
    }
    #pragma unroll
    for (int k = 0; k < 12; ++k) {
      int d = d0 + k;
      #pragma unroll
      for (int i = 0; i < 9; ++i) {
        int ky = i/3, kx = i%3;
        pp1[i] = (d+1 < D_) ? sfus[d+1][py+ky][px+kx] : 0.0f;
      }
      float acc = bias;
      #pragma unroll
      for (int i = 0; i < 9; ++i) acc += pm1[i]*kw[i];
      #pragma unroll
      for (int i = 0; i < 9; ++i) acc += p0[i]*kw[9+i];
      #pragma unroll
      for (int i = 0; i < 9; ++i) acc += pp1[i]*kw[18+i];
      scost[d][pid] = acc;
      #pragma unroll
      for (int i = 0; i < 9; ++i) { pm1[i] = p0[i]; p0[i] = pp1[i]; }
    }
  }
  __syncthreads();

  // phase D: softmax / argmax / outputs, one thread per pixel
  if (tid < 64) {
    int tx = tid & 15, ty = tid >> 4;
    int gx = gx0 + tx, gy = gy0 + ty;
    int gp = gy*W_ + gx;
    float vmax = scost[0][tid];
    int am = 0;
    #pragma unroll
    for (int d = 1; d < D_; ++d) {
      float c = scost[d][tid];
      if (c > vmax) { vmax = c; am = d; }
    }
    float sum = 0.0f;
    #pragma unroll
    for (int d = 0; d < D_; ++d) sum += expf(scost[d][tid] - vmax);
    float inv = 1.0f / sum;
    #pragma unroll
    for (int d = 0; d < D_; ++d)
      out[(size_t)(2*HW) + (size_t)d*HW + gp] = expf(scost[d][tid] - vmax) * inv;
    out[gp] = dv[(size_t)am*HW + gp];
    out[HW + gp] = inv;
    // view_weights output
    int rint = (ty+1)*TXH + (tx+1);
    #pragma unroll
    for (int v = 0; v < NV; ++v)
      out[(size_t)(2*HW + D_*HW) + (size_t)v*HW + gp] = svw[v][rint];
  }
}

// ---------------- launch ----------------
extern "C" void kernel_launch(void* const* d_in, const int* in_sizes, int n_in,
                              void* d_out, int out_size, void* d_ws, size_t ws_size,
                              hipStream_t stream) {
  const float* feat = (const float*)d_in[0];
  const float* pm   = (const float*)d_in[1];
  const float* dv   = (const float*)d_in[2];
  const float* w0   = (const float*)d_in[3];
  const float* b0   = (const float*)d_in[4];
  const float* w1   = (const float*)d_in[5];
  const float* b1   = (const float*)d_in[6];
  const float* w2   = (const float*)d_in[7];
  const float* b2   = (const float*)d_in[8];
  const float* rw   = (const float*)d_in[9];
  const float* rb   = (const float*)d_in[10];
  float* out = (float*)d_out;
  float* ws  = (float*)d_ws;

  // workspace layout (floats)
  float*    xf  = ws;                        // 48 (pad 64)
  float*    tf  = ws + 64;                   // 5*HW*C + 64 zero-pad
  float*    sim = ws + 3276928;              // 4*48*HW = 3,932,160
  unsigned* vwu = (unsigned*)(ws + 7209088); // 4*HW = 81,920
  // high-water mark: ~7.29M floats = ~27.9 MB

  hipLaunchKernelGGL(k_prep, dim3(HW/64, 5), dim3(256), 0, stream,
                     feat, pm, tf, xf, vwu);
  hipLaunchKernelGGL(k_warp, dim3((NV*NCHK*HW*8)/256), dim3(256), 0, stream,
                     tf, dv, xf, sim);
  hipLaunchKernelGGL(k_mlp, dim3((NV*(D_/4)*HW)/256), dim3(256), 0, stream,
                     sim, w0, b0, w1, b1, w2, b2, vwu);
  hipLaunchKernelGGL(k_fct, dim3(W_/TX, H_/TY), dim3(256), 0, stream,
                     sim, vwu, rw, rb, dv, out);
}

// Round 12
// 94.513 us; speedup vs baseline: 1.2377x; 1.2377x over previous
//
#include <hip/hip_runtime.h>
#include <hip/hip_bf16.h>
#include <math.h>

#define W_  160
#define H_  128
#define HW  20480
#define D_  48
#define C_  32
#define NV  4    // source views (views 1..4)
#define DB  8    // depth-block in k_warp

// conv/softmax tile
#define TX  16
#define TY  4
#define TXH 18
#define TYH 6
#define NCOL (TXH*TYH)   // 108

// ---------------- cross-lane helpers ----------------
// 0xB1 = quad_perm [1,0,3,2] (xor 1); 0x4E = quad_perm [2,3,0,1] (xor 2);
// 0x141 = row_half_mirror (lane i <-> 7-i within each 8-lane half-row):
// after xor1+xor2 each quad holds its quad-sum, so half-mirror adds the
// sibling quad -> full 8-lane sum in all 8 lanes. Pure VALU, no LDS pipe.
template<int CTRL>
__device__ __forceinline__ float dpp_add(float s) {
  int t = __builtin_amdgcn_update_dpp(0, __float_as_int(s), CTRL, 0xF, 0xF, true);
  return s + __int_as_float(t);
}

// monotone float<->uint ordering (for atomic max)
__device__ __forceinline__ unsigned ordf(float f) {
  unsigned b = __float_as_uint(f);
  return b ^ (((int)b >> 31) | 0x80000000u);
}
__device__ __forceinline__ float deordf(unsigned u) {
  unsigned b = (u & 0x80000000u) ? (u ^ 0x80000000u) : ~u;
  return __uint_as_float(b);
}

// ---------------- projection helpers ----------------
__device__ __forceinline__ void fuse_proj(const float* pm, float* P) {
  const float* E = pm;
  const float* K = pm + 16;
  for (int r = 0; r < 3; ++r)
    for (int c = 0; c < 4; ++c)
      P[r*4+c] = K[r*4+0]*E[0*4+c] + K[r*4+1]*E[1*4+c] + K[r*4+2]*E[2*4+c];
  for (int c = 0; c < 4; ++c) P[12+c] = E[12+c];
}

__device__ void invert4(const float* m, float* invOut) {
  float inv[16];
  inv[0]  =  m[5]*m[10]*m[15] - m[5]*m[11]*m[14] - m[9]*m[6]*m[15] + m[9]*m[7]*m[14] + m[13]*m[6]*m[11] - m[13]*m[7]*m[10];
  inv[4]  = -m[4]*m[10]*m[15] + m[4]*m[11]*m[14] + m[8]*m[6]*m[15] - m[8]*m[7]*m[14] - m[12]*m[6]*m[11] + m[12]*m[7]*m[10];
  inv[8]  =  m[4]*m[9]*m[15]  - m[4]*m[11]*m[13] - m[8]*m[5]*m[15] + m[8]*m[7]*m[13] + m[12]*m[5]*m[11] - m[12]*m[7]*m[9];
  inv[12] = -m[4]*m[9]*m[14]  + m[4]*m[10]*m[13] + m[8]*m[5]*m[14] - m[8]*m[6]*m[13] - m[12]*m[5]*m[10] + m[12]*m[6]*m[9];
  inv[1]  = -m[1]*m[10]*m[15] + m[1]*m[11]*m[14] + m[9]*m[2]*m[15] - m[9]*m[3]*m[14] - m[13]*m[2]*m[11] + m[13]*m[3]*m[10];
  inv[5]  =  m[0]*m[10]*m[15] - m[0]*m[11]*m[14] - m[8]*m[2]*m[15] + m[8]*m[3]*m[14] + m[12]*m[2]*m[11] - m[12]*m[3]*m[10];
  inv[9]  = -m[0]*m[9]*m[15]  + m[0]*m[11]*m[13] + m[8]*m[1]*m[15] - m[8]*m[3]*m[13] - m[12]*m[1]*m[11] + m[12]*m[3]*m[9];
  inv[13] =  m[0]*m[9]*m[14]  - m[0]*m[10]*m[13] - m[8]*m[1]*m[14] + m[8]*m[2]*m[13] + m[12]*m[1]*m[10] - m[12]*m[2]*m[9];
  inv[2]  =  m[1]*m[6]*m[15]  - m[1]*m[7]*m[14]  - m[5]*m[2]*m[15] + m[5]*m[3]*m[14] + m[13]*m[2]*m[7]  - m[13]*m[3]*m[6];
  inv[6]  = -m[0]*m[6]*m[15]  + m[0]*m[7]*m[14]  + m[4]*m[2]*m[15] - m[4]*m[3]*m[14] - m[12]*m[2]*m[7]  + m[12]*m[3]*m[6];
  inv[10] =  m[0]*m[5]*m[15]  - m[0]*m[7]*m[13]  - m[4]*m[1]*m[15] + m[4]*m[3]*m[13] + m[12]*m[1]*m[7]  - m[12]*m[3]*m[5];
  inv[14] = -m[0]*m[5]*m[14]  + m[0]*m[6]*m[13]  + m[4]*m[1]*m[14] - m[4]*m[2]*m[13] - m[12]*m[1]*m[6]  + m[12]*m[2]*m[5];
  inv[3]  = -m[1]*m[6]*m[11]  + m[1]*m[7]*m[10]  + m[5]*m[2]*m[11] - m[5]*m[3]*m[10] - m[9]*m[2]*m[7]   + m[9]*m[3]*m[6];
  inv[7]  =  m[0]*m[6]*m[11]  - m[0]*m[7]*m[10]  - m[4]*m[2]*m[11] + m[4]*m[3]*m[10] + m[8]*m[2]*m[7]   - m[8]*m[3]*m[6];
  inv[11] = -m[0]*m[5]*m[11]  + m[0]*m[7]*m[9]   + m[4]*m[1]*m[11] - m[4]*m[3]*m[9]  - m[8]*m[1]*m[7]   + m[8]*m[3]*m[5];
  inv[15] =  m[0]*m[5]*m[10]  - m[0]*m[6]*m[9]   - m[4]*m[1]*m[10] + m[4]*m[2]*m[9]  + m[8]*m[1]*m[6]   - m[8]*m[2]*m[5];
  float det = m[0]*inv[0] + m[1]*inv[4] + m[2]*inv[8] + m[3]*inv[12];
  det = 1.0f / det;
  for (int i = 0; i < 16; i++) invOut[i] = inv[i] * det;
}

// ---------------- prep: transpose + xform + zero pads/accumulators ---------
__global__ void __launch_bounds__(256)
k_prep(const float* __restrict__ feat, const float* __restrict__ pm,
       float* __restrict__ tf, float* __restrict__ xf,
       unsigned* __restrict__ vwu) {
  __shared__ float tile[C_][64+1];
  int v  = blockIdx.y;
  int p0 = blockIdx.x * 64;
  int t  = threadIdx.x;

  if (v == 0) vwu[blockIdx.x*256 + t] = 0u;

  int pl = t & 63;
  int cg = t >> 6;            // 0..3
  const float* src = feat + (size_t)v*C_*HW + p0 + pl;
  #pragma unroll
  for (int k = 0; k < 8; ++k) {
    int c = cg*8 + k;
    tile[c][pl] = src[(size_t)c*HW];
  }
  __syncthreads();

  int pp = t >> 2;            // pixel 0..63
  int co = (t & 3) * 8;       // channel offset
  float4 a, b;
  a.x = tile[co+0][pp]; a.y = tile[co+1][pp]; a.z = tile[co+2][pp]; a.w = tile[co+3][pp];
  b.x = tile[co+4][pp]; b.y = tile[co+5][pp]; b.z = tile[co+6][pp]; b.w = tile[co+7][pp];
  float* dst = tf + ((size_t)v*HW + p0 + pp)*C_ + co;
  *(float4*)dst = a;
  *(float4*)(dst+4) = b;

  if (blockIdx.x == 0 && v == 0) {
    if (t < 64) tf[(size_t)5*HW*C_ + t] = 0.0f;   // zero pad (invalid corners)
    if (t == 0) {
      float Pr[16], Pinv[16], Ps[16], M[16];
      fuse_proj(pm, Pr);
      invert4(Pr, Pinv);
      for (int vv = 1; vv <= NV; ++vv) {
        fuse_proj(pm + vv*32, Ps);
        for (int r = 0; r < 4; ++r)
          for (int c = 0; c < 4; ++c) {
            float acc = 0.f;
            for (int k = 0; k < 4; ++k) acc += Ps[r*4+k]*Pinv[k*4+c];
            M[r*4+c] = acc;
          }
        float* o = xf + (vv-1)*12;
        o[0]=M[0];  o[1]=M[1];  o[2]=M[2];
        o[3]=M[4];  o[4]=M[5];  o[5]=M[6];
        o[6]=M[8];  o[7]=M[9];  o[8]=M[10];
        o[9]=M[3];  o[10]=M[7]; o[11]=M[11];
      }
    }
  }
}

// ---------------- main warp + similarity kernel ----------------
// Wave = 8 pixels x 8 slots; one wave owns all 48 depths of its pixels.
// Per 8-depth block:
//   phase 1: each lane builds the descriptor (4 corner byte offsets + 4
//            bilinear weights pre-scaled 1/C via rfc, shared exact 1/Z) for
//            ONE (pixel,depth) item, staged to LDS (xor-swizzled).
//   phase 2: per depth, 2 b128 LDS reads; PER-LANE corner-reuse predication:
//            `if (m)` is exec-masked per 8-lane pixel group, so the TA only
//            processes lines of pixels that actually moved (~10%/depth),
//            vs wave-level __any (~50%/depth). Reduce = pure-DPP butterfly
//            (xor1, xor2, half-mirror) -- no LDS pipe in the hot path.
__global__ void __launch_bounds__(256)
k_warp(const float* __restrict__ tf, const float* __restrict__ dv,
       const float* __restrict__ xf, float* __restrict__ sim_all) {
  __shared__ int4   dso[4][64];
  __shared__ float4 dsw[4][64];

  int lane = threadIdx.x & 63;
  int wv = threadIdx.x >> 6;
  int ch = lane & 7;              // channel chunk (phase 2) / depth slot (phase 1)
  int pix = (lane >> 3) & 7;      // pixel within group
  int wvg = __builtin_amdgcn_readfirstlane((blockIdx.x*256 + threadIdx.x) >> 6);
  const int PGPV = HW/8;
  int pg = wvg % PGPV;
  int v  = wvg / PGPV;
  int p  = pg*8 + pix;

  float xpix = (float)(p % W_);
  float ypix = (float)(p / W_);

  const float* M = xf + v*12;
  float rx = M[0]*xpix + M[1]*ypix + M[2];
  float ry = M[3]*xpix + M[4]*ypix + M[5];
  float rz = M[6]*xpix + M[7]*ypix + M[8];
  float t0 = M[9], t1 = M[10], t2 = M[11];

  // ref fragment, pre-scaled by 1/C (folds the sim normalization)
  float4 rfc = *(const float4*)(tf + (size_t)p*C_ + ch*4);
  rfc.x *= (1.0f/(float)C_); rfc.y *= (1.0f/(float)C_);
  rfc.z *= (1.0f/(float)C_); rfc.w *= (1.0f/(float)C_);

  const char* tfb = (const char*)(tf + (size_t)(v+1)*HW*C_);
  const int chb = ch*16;
  const int ZB = (4-v)*HW*C_*4;   // byte offset (from view base) of zero pad

  float* simv = sim_all + (size_t)v*D_*HW + p;

  int4 P = make_int4(-1,-1,-1,-1);
  float d00 = 0.f, d01 = 0.f, d10 = 0.f, d11 = 0.f;

  for (int b = 0; b < D_/DB; ++b) {
    // ---- phase 1: one descriptor per lane, staged to LDS ----
    int d1 = b*DB + ch;
    float dep = dv[(size_t)d1*HW + p];
    float Z  = rz*dep + t2;
    float zr = 1.0f / Z;                // exact reciprocal, shared by px,py
    float px = (rx*dep + t0) * zr;
    float py = (ry*dep + t1) * zr;
    float x0f = floorf(px), y0f = floorf(py);
    float wx1 = px - x0f;
    float wy1 = py - y0f;
    float wx0 = 1.0f - wx1, wy0 = 1.0f - wy1;
    int x0 = (int)x0f, y0 = (int)y0f;
    int x1 = x0 + 1,   y1 = y0 + 1;
    bool vx0 = ((unsigned)x0 <= (unsigned)(W_-1));
    bool vx1 = ((unsigned)x1 <= (unsigned)(W_-1));
    bool vy0 = ((unsigned)y0 <= (unsigned)(H_-1));
    bool vy1 = ((unsigned)y1 <= (unsigned)(H_-1));
    int cx0 = min(max(x0, 0), W_-1);
    int cx1 = min(max(x1, 0), W_-1);
    int cy0 = min(max(y0, 0), H_-1);
    int cy1 = min(max(y1, 0), H_-1);
    int r0 = cy0*W_, r1 = cy1*W_;
    int o00 = (vx0 && vy0) ? (r0+cx0)*(C_*4) : ZB;
    int o01 = (vx1 && vy0) ? (r0+cx1)*(C_*4) : ZB;
    int o10 = (vx0 && vy1) ? (r1+cx0)*(C_*4) : ZB;
    int o11 = (vx1 && vy1) ? (r1+cx1)*(C_*4) : ZB;

    int key = (ch<<3) | (pix ^ ch);          // bank-uniform for write & read
    dso[wv][key] = make_int4(o00, o01, o10, o11);
    dsw[wv][key] = make_float4(wx0*wy0, wx1*wy0, wx0*wy1, wx1*wy1);

    // ---- phase 2: 8 depths; descriptor via 2 b128 LDS reads ----
    #pragma unroll
    for (int dd = 0; dd < DB; ++dd) {
      int it = (dd<<3) | (pix ^ dd);
      int4   O  = dso[wv][it];
      float4 Wt = dsw[wv][it];

      bool m = (O.x != P.x) || (O.y != P.y) || (O.z != P.z) || (O.w != P.w);
      if (m) {   // per-lane predication: TA processes only moved pixels' lines
        float4 a  = *(const float4*)(tfb + (O.x + chb));
        float4 bq = *(const float4*)(tfb + (O.y + chb));
        float4 g  = *(const float4*)(tfb + (O.z + chb));
        float4 e  = *(const float4*)(tfb + (O.w + chb));
        d00 = a.x*rfc.x  + a.y*rfc.y  + a.z*rfc.z  + a.w*rfc.w;
        d01 = bq.x*rfc.x + bq.y*rfc.y + bq.z*rfc.z + bq.w*rfc.w;
        d10 = g.x*rfc.x  + g.y*rfc.y  + g.z*rfc.z  + g.w*rfc.w;
        d11 = e.x*rfc.x  + e.y*rfc.y  + e.z*rfc.z  + e.w*rfc.w;
      }
      P = O;

      float s = Wt.x*d00 + Wt.y*d01 + Wt.z*d10 + Wt.w*d11;
      s = dpp_add<0xB1>(s);    // xor 1 (quad_perm)
      s = dpp_add<0x4E>(s);    // xor 2 (quad_perm)
      s = dpp_add<0x141>(s);   // row_half_mirror: adds sibling quad
      if (ch == 0) simv[(size_t)(b*DB + dd)*HW] = s;
    }
  }
}

// ---------------- MLP: 4 depths per thread, atomic-max logit -------------
__global__ void __launch_bounds__(256)
k_mlp(const float* __restrict__ sim_all,
      const float* __restrict__ w0, const float* __restrict__ b0,
      const float* __restrict__ w1, const float* __restrict__ b1,
      const float* __restrict__ w2, const float* __restrict__ b2,
      unsigned* __restrict__ vwu) {
  int idx = blockIdx.x*blockDim.x + threadIdx.x;
  if (idx >= NV*(D_/4)*HW) return;
  int p = idx % HW;
  int t = idx / HW;           // (v, chunk)
  int v = t / (D_/4);
  int c = t % (D_/4);

  const float* sp_ = sim_all + ((size_t)(v*D_ + c*4))*HW + p;
  float sv[4];
  sv[0] = sp_[0];
  sv[1] = sp_[HW];
  sv[2] = sp_[2*HW];
  sv[3] = sp_[3*HW];

  float ymax = -3.0e38f;
  #pragma unroll
  for (int k = 0; k < 4; ++k) {
    float s = sv[k];
    float acc0 = b1[0], acc1 = b1[1], acc2 = b1[2], acc3 = b1[3];
    float acc4 = b1[4], acc5 = b1[5], acc6 = b1[6], acc7 = b1[7];
    #pragma unroll
    for (int o = 0; o < 16; ++o) {
      float h = fmaxf(fmaf(w0[o], s, b0[o]), 0.0f);
      acc0 = fmaf(w1[0*16+o], h, acc0);
      acc1 = fmaf(w1[1*16+o], h, acc1);
      acc2 = fmaf(w1[2*16+o], h, acc2);
      acc3 = fmaf(w1[3*16+o], h, acc3);
      acc4 = fmaf(w1[4*16+o], h, acc4);
      acc5 = fmaf(w1[5*16+o], h, acc5);
      acc6 = fmaf(w1[6*16+o], h, acc6);
      acc7 = fmaf(w1[7*16+o], h, acc7);
    }
    float yv = b2[0];
    yv = fmaf(w2[0], fmaxf(acc0, 0.0f), yv);
    yv = fmaf(w2[1], fmaxf(acc1, 0.0f), yv);
    yv = fmaf(w2[2], fmaxf(acc2, 0.0f), yv);
    yv = fmaf(w2[3], fmaxf(acc3, 0.0f), yv);
    yv = fmaf(w2[4], fmaxf(acc4, 0.0f), yv);
    yv = fmaf(w2[5], fmaxf(acc5, 0.0f), yv);
    yv = fmaf(w2[6], fmaxf(acc6, 0.0f), yv);
    yv = fmaf(w2[7], fmaxf(acc7, 0.0f), yv);
    ymax = fmaxf(ymax, yv);
  }
  atomicMax(&vwu[(size_t)v*HW + p], ordf(ymax));
}

// ---------------- fused: vw-decode + fuse + conv + softmax/argmax ----------
__global__ void __launch_bounds__(256)
k_fct(const float* __restrict__ sim_all, const unsigned* __restrict__ vwu,
      const float* __restrict__ rw, const float* __restrict__ rb,
      const float* __restrict__ dv, float* __restrict__ out) {
  __shared__ float sfus[D_][TYH][TXH+1];
  __shared__ float scost[D_][64];
  __shared__ float svw[NV][NCOL];
  __shared__ float sinvw[NCOL];
  __shared__ int   sgpc[NCOL];

  int tid = threadIdx.x;
  int gx0 = blockIdx.x*TX;
  int gy0 = blockIdx.y*TY;

  // phase A: per-column view weights (decode + sigmoid) / inv wsum / pixel idx
  if (tid < NCOL) {
    int yy = tid / TXH, xx = tid % TXH;
    int gy = gy0 + yy - 1, gx = gx0 + xx - 1;
    bool valid = (gx >= 0) && (gx < W_) && (gy >= 0) && (gy < H_);
    int gp = min(max(gy,0),H_-1)*W_ + min(max(gx,0),W_-1);
    sgpc[tid] = gp;
    float a0 = 1.0f/(1.0f + expf(-deordf(vwu[0*HW+gp])));
    float a1 = 1.0f/(1.0f + expf(-deordf(vwu[1*HW+gp])));
    float a2 = 1.0f/(1.0f + expf(-deordf(vwu[2*HW+gp])));
    float a3 = 1.0f/(1.0f + expf(-deordf(vwu[3*HW+gp])));
    float inv = valid ? 1.0f/(1e-5f + a0+a1+a2+a3) : 0.0f;
    if (!valid) { a0=a1=a2=a3=0.f; }
    svw[0][tid]=a0; svw[1][tid]=a1; svw[2][tid]=a2; svw[3][tid]=a3;
    sinvw[tid] = inv;
  }
  __syncthreads();

  // phase B: fill fused volume tile (invalid columns auto-zero via weights)
  for (int j = tid; j < D_*NCOL; j += 256) {
    int d = j / NCOL, r = j % NCOL;
    int gp = sgpc[r];
    float s0 = sim_all[(size_t)(0*D_+d)*HW + gp];
    float s1 = sim_all[(size_t)(1*D_+d)*HW + gp];
    float s2 = sim_all[(size_t)(2*D_+d)*HW + gp];
    float s3 = sim_all[(size_t)(3*D_+d)*HW + gp];
    float val = (s0*svw[0][r] + s1*svw[1][r] + s2*svw[2][r] + s3*svw[3][r]) * sinvw[r];
    int yy = r / TXH, xx = r % TXH;
    sfus[d][yy][xx] = val;
  }
  __syncthreads();

  // phase C: 3x3x3 conv; thread = (pixel, depth-group of 12)
  {
    int pid = tid & 63;
    int dg  = tid >> 6;
    int px = pid & 15, py = pid >> 4;
    float kw[27];
    #pragma unroll
    for (int i = 0; i < 27; ++i) kw[i] = rw[i];
    float bias = rb[0];

    float pm1[9], p0[9], pp1[9];
    int d0 = dg*12;
    #pragma unroll
    for (int i = 0; i < 9; ++i) {
      int ky = i/3, kx = i%3;
      pm1[i] = (d0 > 0) ? sfus[d0-1][py+ky][px+kx] : 0.0f;
      p0[i]  = sfus[d0][py+ky][px+kx];
    }
    #pragma unroll
    for (int k = 0; k < 12; ++k) {
      int d = d0 + k;
      #pragma unroll
      for (int i = 0; i < 9; ++i) {
        int ky = i/3, kx = i%3;
        pp1[i] = (d+1 < D_) ? sfus[d+1][py+ky][px+kx] : 0.0f;
      }
      float acc = bias;
      #pragma unroll
      for (int i = 0; i < 9; ++i) acc += pm1[i]*kw[i];
      #pragma unroll
      for (int i = 0; i < 9; ++i) acc += p0[i]*kw[9+i];
      #pragma unroll
      for (int i = 0; i < 9; ++i) acc += pp1[i]*kw[18+i];
      scost[d][pid] = acc;
      #pragma unroll
      for (int i = 0; i < 9; ++i) { pm1[i] = p0[i]; p0[i] = pp1[i]; }
    }
  }
  __syncthreads();

  // phase D: softmax / argmax / outputs, one thread per pixel (single exp pass)
  if (tid < 64) {
    int tx = tid & 15, ty = tid >> 4;
    int gx = gx0 + tx, gy = gy0 + ty;
    int gp = gy*W_ + gx;
    float vmax = scost[0][tid];
    int am = 0;
    #pragma unroll
    for (int d = 1; d < D_; ++d) {
      float c = scost[d][tid];
      if (c > vmax) { vmax = c; am = d; }
    }
    float sum = 0.0f;
    #pragma unroll
    for (int d = 0; d < D_; ++d) {
      float e = expf(scost[d][tid] - vmax);
      scost[d][tid] = e;         // each thread owns column tid
      sum += e;
    }
    float inv = 1.0f / sum;
    #pragma unroll
    for (int d = 0; d < D_; ++d)
      out[(size_t)(2*HW) + (size_t)d*HW + gp] = scost[d][tid] * inv;
    out[gp] = dv[(size_t)am*HW + gp];
    out[HW + gp] = inv;
    // view_weights output
    int rint = (ty+1)*TXH + (tx+1);
    #pragma unroll
    for (int v = 0; v < NV; ++v)
      out[(size_t)(2*HW + D_*HW) + (size_t)v*HW + gp] = svw[v][rint];
  }
}

// ---------------- launch ----------------
extern "C" void kernel_launch(void* const* d_in, const int* in_sizes, int n_in,
                              void* d_out, int out_size, void* d_ws, size_t ws_size,
                              hipStream_t stream) {
  const float* feat = (const float*)d_in[0];
  const float* pm   = (const float*)d_in[1];
  const float* dv   = (const float*)d_in[2];
  const float* w0   = (const float*)d_in[3];
  const float* b0   = (const float*)d_in[4];
  const float* w1   = (const float*)d_in[5];
  const float* b1   = (const float*)d_in[6];
  const float* w2   = (const float*)d_in[7];
  const float* b2   = (const float*)d_in[8];
  const float* rw   = (const float*)d_in[9];
  const float* rb   = (const float*)d_in[10];
  float* out = (float*)d_out;
  float* ws  = (float*)d_ws;

  // workspace layout (floats)
  float*    xf  = ws;                        // 48 (pad 64)
  float*    tf  = ws + 64;                   // 5*HW*C + 64 zero-pad
  float*    sim = ws + 3276928;              // 4*48*HW = 3,932,160
  unsigned* vwu = (unsigned*)(ws + 7209088); // 4*HW = 81,920
  // high-water mark: ~7.29M floats = ~27.9 MB

  hipLaunchKernelGGL(k_prep, dim3(HW/64, 5), dim3(256), 0, stream,
                     feat, pm, tf, xf, vwu);
  hipLaunchKernelGGL(k_warp, dim3((NV*HW*8)/256), dim3(256), 0, stream,
                     tf, dv, xf, sim);
  hipLaunchKernelGGL(k_mlp, dim3((NV*(D_/4)*HW)/256), dim3(256), 0, stream,
                     sim, w0, b0, w1, b1, w2, b2, vwu);
  hipLaunchKernelGGL(k_fct, dim3(W_/TX, H_/TY), dim3(256), 0, stream,
                     sim, vwu, rw, rb, dv, out);
}

// Round 13
// 74.787 us; speedup vs baseline: 1.5642x; 1.2638x over previous
//
#include <hip/hip_runtime.h>
#include <hip/hip_bf16.h>
#include <math.h>

#define W_  160
#define H_  128
#define HW  20480
#define D_  48
#define C_  32
#define NV  4    // source views (views 1..4)

// conv/softmax tile
#define TX  16
#define TY  4
#define TXH 18
#define TYH 6
#define NCOL (TXH*TYH)   // 108

// ---------------- cross-lane helpers ----------------
// 0xB1 = quad_perm [1,0,3,2] (xor 1); 0x4E = quad_perm [2,3,0,1] (xor 2);
// 0x141 = row_half_mirror: after xor1+xor2 each quad holds its quad-sum,
// half-mirror adds the sibling quad -> full 8-lane sum in all 8 lanes.
template<int CTRL>
__device__ __forceinline__ float dpp_add(float s) {
  int t = __builtin_amdgcn_update_dpp(0, __float_as_int(s), CTRL, 0xF, 0xF, true);
  return s + __int_as_float(t);
}

// monotone float<->uint ordering (for atomic max)
__device__ __forceinline__ unsigned ordf(float f) {
  unsigned b = __float_as_uint(f);
  return b ^ (((int)b >> 31) | 0x80000000u);
}
__device__ __forceinline__ float deordf(unsigned u) {
  unsigned b = (u & 0x80000000u) ? (u ^ 0x80000000u) : ~u;
  return __uint_as_float(b);
}

// ---------------- projection helpers ----------------
__device__ __forceinline__ void fuse_proj(const float* pm, float* P) {
  const float* E = pm;
  const float* K = pm + 16;
  for (int r = 0; r < 3; ++r)
    for (int c = 0; c < 4; ++c)
      P[r*4+c] = K[r*4+0]*E[0*4+c] + K[r*4+1]*E[1*4+c] + K[r*4+2]*E[2*4+c];
  for (int c = 0; c < 4; ++c) P[12+c] = E[12+c];
}

__device__ void invert4(const float* m, float* invOut) {
  float inv[16];
  inv[0]  =  m[5]*m[10]*m[15] - m[5]*m[11]*m[14] - m[9]*m[6]*m[15] + m[9]*m[7]*m[14] + m[13]*m[6]*m[11] - m[13]*m[7]*m[10];
  inv[4]  = -m[4]*m[10]*m[15] + m[4]*m[11]*m[14] + m[8]*m[6]*m[15] - m[8]*m[7]*m[14] - m[12]*m[6]*m[11] + m[12]*m[7]*m[10];
  inv[8]  =  m[4]*m[9]*m[15]  - m[4]*m[11]*m[13] - m[8]*m[5]*m[15] + m[8]*m[7]*m[13] + m[12]*m[5]*m[11] - m[12]*m[7]*m[9];
  inv[12] = -m[4]*m[9]*m[14]  + m[4]*m[10]*m[13] + m[8]*m[5]*m[14] - m[8]*m[6]*m[13] - m[12]*m[5]*m[10] + m[12]*m[6]*m[9];
  inv[1]  = -m[1]*m[10]*m[15] + m[1]*m[11]*m[14] + m[9]*m[2]*m[15] - m[9]*m[3]*m[14] - m[13]*m[2]*m[11] + m[13]*m[3]*m[10];
  inv[5]  =  m[0]*m[10]*m[15] - m[0]*m[11]*m[14] - m[8]*m[2]*m[15] + m[8]*m[3]*m[14] + m[12]*m[2]*m[11] - m[12]*m[3]*m[10];
  inv[9]  = -m[0]*m[9]*m[15]  + m[0]*m[11]*m[13] + m[8]*m[1]*m[15] - m[8]*m[3]*m[13] - m[12]*m[1]*m[11] + m[12]*m[3]*m[9];
  inv[13] =  m[0]*m[9]*m[14]  - m[0]*m[10]*m[13] - m[8]*m[1]*m[14] + m[8]*m[2]*m[13] + m[12]*m[1]*m[10] - m[12]*m[2]*m[9];
  inv[2]  =  m[1]*m[6]*m[15]  - m[1]*m[7]*m[14]  - m[5]*m[2]*m[15] + m[5]*m[3]*m[14] + m[13]*m[2]*m[7]  - m[13]*m[3]*m[6];
  inv[6]  = -m[0]*m[6]*m[15]  + m[0]*m[7]*m[14]  + m[4]*m[2]*m[15] - m[4]*m[3]*m[14] - m[12]*m[2]*m[7]  + m[12]*m[3]*m[6];
  inv[10] =  m[0]*m[5]*m[15]  - m[0]*m[7]*m[13]  - m[4]*m[1]*m[15] + m[4]*m[3]*m[13] + m[12]*m[1]*m[7]  - m[12]*m[3]*m[5];
  inv[14] = -m[0]*m[5]*m[14]  + m[0]*m[6]*m[13]  + m[4]*m[1]*m[14] - m[4]*m[2]*m[13] - m[12]*m[1]*m[6]  + m[12]*m[2]*m[5];
  inv[3]  = -m[1]*m[6]*m[11]  + m[1]*m[7]*m[10]  + m[5]*m[2]*m[11] - m[5]*m[3]*m[10] - m[9]*m[2]*m[7]   + m[9]*m[3]*m[6];
  inv[7]  =  m[0]*m[6]*m[11]  - m[0]*m[7]*m[10]  - m[4]*m[2]*m[11] + m[4]*m[3]*m[10] + m[8]*m[2]*m[7]   - m[8]*m[3]*m[6];
  inv[11] = -m[0]*m[5]*m[11]  + m[0]*m[7]*m[9]   + m[4]*m[1]*m[11] - m[4]*m[3]*m[9]  - m[8]*m[1]*m[7]   + m[8]*m[3]*m[5];
  inv[15] =  m[0]*m[5]*m[10]  - m[0]*m[6]*m[9]   - m[4]*m[1]*m[10] + m[4]*m[2]*m[9]  + m[8]*m[1]*m[6]   - m[8]*m[2]*m[5];
  float det = m[0]*inv[0] + m[1]*inv[4] + m[2]*inv[8] + m[3]*inv[12];
  det = 1.0f / det;
  for (int i = 0; i < 16; i++) invOut[i] = inv[i] * det;
}

// ---------------- prep: transpose + xform + zero pads/accumulators ---------
__global__ void __launch_bounds__(256)
k_prep(const float* __restrict__ feat, const float* __restrict__ pm,
       float* __restrict__ tf, float* __restrict__ xf,
       unsigned* __restrict__ vwu) {
  __shared__ float tile[C_][64+1];
  int v  = blockIdx.y;
  int p0 = blockIdx.x * 64;
  int t  = threadIdx.x;

  if (v == 0) vwu[blockIdx.x*256 + t] = 0u;

  int pl = t & 63;
  int cg = t >> 6;            // 0..3
  const float* src = feat + (size_t)v*C_*HW + p0 + pl;
  #pragma unroll
  for (int k = 0; k < 8; ++k) {
    int c = cg*8 + k;
    tile[c][pl] = src[(size_t)c*HW];
  }
  __syncthreads();

  int pp = t >> 2;            // pixel 0..63
  int co = (t & 3) * 8;       // channel offset
  float4 a, b;
  a.x = tile[co+0][pp]; a.y = tile[co+1][pp]; a.z = tile[co+2][pp]; a.w = tile[co+3][pp];
  b.x = tile[co+4][pp]; b.y = tile[co+5][pp]; b.z = tile[co+6][pp]; b.w = tile[co+7][pp];
  float* dst = tf + ((size_t)v*HW + p0 + pp)*C_ + co;
  *(float4*)dst = a;
  *(float4*)(dst+4) = b;

  if (blockIdx.x == 0 && v == 0) {
    if (t < 64) tf[(size_t)5*HW*C_ + t] = 0.0f;   // zero pad (invalid corners)
    if (t == 0) {
      float Pr[16], Pinv[16], Ps[16], M[16];
      fuse_proj(pm, Pr);
      invert4(Pr, Pinv);
      for (int vv = 1; vv <= NV; ++vv) {
        fuse_proj(pm + vv*32, Ps);
        for (int r = 0; r < 4; ++r)
          for (int c = 0; c < 4; ++c) {
            float acc = 0.f;
            for (int k = 0; k < 4; ++k) acc += Ps[r*4+k]*Pinv[k*4+c];
            M[r*4+c] = acc;
          }
        float* o = xf + (vv-1)*12;
        o[0]=M[0];  o[1]=M[1];  o[2]=M[2];
        o[3]=M[4];  o[4]=M[5];  o[5]=M[6];
        o[6]=M[8];  o[7]=M[9];  o[8]=M[10];
        o[9]=M[3];  o[10]=M[7]; o[11]=M[11];
      }
    }
  }
}

// ---------------- texel-dot table builder (fast path) ----------------
// KX texel columns x 3 rows per pixel. Each lane computes the dot of its
// 4-channel slice with every texel, DPP-reduces across the 8 ch-lanes,
// and the lane with ch == t%8 writes the full dot to LDS.
template<int KX>
__device__ __forceinline__ void build_tab(
    const char* tfb, int chb, int ZB, float4 rfc,
    int xmin, int ymin, int ch, float* tabp /* dtab[wv][pix] */) {
  #pragma unroll
  for (int t = 0; t < KX*3; ++t) {
    int xi = xmin + t/3;
    int yi = ymin + t%3;
    bool valid = ((unsigned)xi < (unsigned)W_) && ((unsigned)yi < (unsigned)H_);
    int off = valid ? (yi*W_ + xi)*(C_*4) : ZB;
    float4 a = *(const float4*)(tfb + off + chb);
    float d = a.x*rfc.x + a.y*rfc.y + a.z*rfc.z + a.w*rfc.w;
    d = dpp_add<0xB1>(d);
    d = dpp_add<0x4E>(d);
    d = dpp_add<0x141>(d);
    if (ch == (t & 7)) tabp[t] = d;
  }
}

// ---------------- main warp + similarity kernel ----------------
// Wave = 8 pixels x 8 lanes/pixel. px(dep) is a Mobius function of dep ->
// monotone, so over the sweep each pixel's bilinear corners live in a small
// window bounded by the ENDPOINT projections (here Nx<=~6, Ny<=3).
//   stage 1: project d=0 and d=47 -> window (xmin,ymin,Nx,Ny). Wave votes
//            fast/fallback (budget Nx<=8, Ny<=3, deps within endpoints,
//            no Z pole).
//   stage 2: build per-pixel texel-dot table (each texel dot computed ONCE).
//   stage 3: per lane 6 depths (d = 8k+ch), fully independent, branch-free:
//            project, clamp floor into window (continuity => ~1e-7 error at
//            texel boundaries), 4 broadcast LDS table reads, weighted sum,
//            store. No loop-carried deps -> deep pipelining.
__global__ void __launch_bounds__(256)
k_warp(const float* __restrict__ tf, const float* __restrict__ dv,
       const float* __restrict__ xf, float* __restrict__ sim_all) {
  __shared__ float dtab[4][8][25];   // 25-stride: conflict-free across pixels

  int lane = threadIdx.x & 63;
  int wv = threadIdx.x >> 6;
  int ch = lane & 7;              // lane-within-pixel (channel slice / depth slot)
  int pix = (lane >> 3) & 7;      // pixel within group
  int wvg = __builtin_amdgcn_readfirstlane((blockIdx.x*256 + threadIdx.x) >> 6);
  const int PGPV = HW/8;
  int pg = wvg % PGPV;
  int v  = wvg / PGPV;
  int p  = pg*8 + pix;

  float xpix = (float)(p % W_);
  float ypix = (float)(p / W_);

  const float* M = xf + v*12;
  float rx = M[0]*xpix + M[1]*ypix + M[2];
  float ry = M[3]*xpix + M[4]*ypix + M[5];
  float rz = M[6]*xpix + M[7]*ypix + M[8];
  float t0 = M[9], t1 = M[10], t2 = M[11];

  // ref fragment, pre-scaled by 1/C (folds the sim normalization)
  float4 rfc = *(const float4*)(tf + (size_t)p*C_ + ch*4);
  rfc.x *= (1.0f/(float)C_); rfc.y *= (1.0f/(float)C_);
  rfc.z *= (1.0f/(float)C_); rfc.w *= (1.0f/(float)C_);

  const char* tfb = (const char*)(tf + (size_t)(v+1)*HW*C_);
  const int chb = ch*16;
  const int ZB = (4-v)*HW*C_*4;   // byte offset (from view base) of zero pad

  // deps: endpoints + this lane's 6 depths
  float depE0 = dv[p];
  float depE1 = dv[(size_t)47*HW + p];
  float dpk[6];
  #pragma unroll
  for (int k = 0; k < 6; ++k) dpk[k] = dv[(size_t)(k*8 + ch)*HW + p];

  // endpoint projections -> window
  float Z0 = rz*depE0 + t2, Z1 = rz*depE1 + t2;
  float iz0 = 1.0f / Z0,     iz1 = 1.0f / Z1;
  float pxa = (rx*depE0 + t0) * iz0, pya = (ry*depE0 + t1) * iz0;
  float pxb = (rx*depE1 + t0) * iz1, pyb = (ry*depE1 + t1) * iz1;
  int xmin = (int)floorf(fminf(pxa, pxb));
  int ymin = (int)floorf(fminf(pya, pyb));
  int Nx = (int)floorf(fmaxf(pxa, pxb)) - xmin + 2;
  int Ny = (int)floorf(fmaxf(pya, pyb)) - ymin + 2;

  float dmn = fminf(depE0, depE1), dmx = fmaxf(depE0, depE1);
  bool ok = (Nx <= 8) && (Ny <= 3) && (Z0*Z1 > 0.0f);
  #pragma unroll
  for (int k = 0; k < 6; ++k) ok = ok && (dpk[k] >= dmn) && (dpk[k] <= dmx);

  float* simv = sim_all + (size_t)v*D_*HW + p;

  if (__all(ok)) {
    // ---- fast path ----
    float* tabp = dtab[wv][pix];
    if (__all(Nx <= 5)) build_tab<5>(tfb, chb, ZB, rfc, xmin, ymin, ch, tabp);
    else                build_tab<8>(tfb, chb, ZB, rfc, xmin, ymin, ch, tabp);

    int xhi = xmin + 6;   // clamp ceiling for floor (KX=8 => xi <= xmin+6)
    if (__all(Nx <= 5)) xhi = xmin + 3;

    #pragma unroll
    for (int k = 0; k < 6; ++k) {
      float dep = dpk[k];
      float Z  = rz*dep + t2;
      float zr = 1.0f / Z;
      float px = (rx*dep + t0) * zr;
      float py = (ry*dep + t1) * zr;
      int xi = (int)floorf(px);
      int yi = (int)floorf(py);
      xi = min(max(xi, xmin), xhi);
      yi = min(max(yi, ymin), ymin + 1);
      float wx1 = px - (float)xi;
      float wy1 = py - (float)yi;
      float wx0 = 1.0f - wx1, wy0 = 1.0f - wy1;
      int idx = (xi - xmin)*3 + (yi - ymin);
      float t00 = tabp[idx];
      float t01 = tabp[idx + 3];
      float t10 = tabp[idx + 1];
      float t11 = tabp[idx + 4];
      float s = wx0*wy0*t00 + wx1*wy0*t01 + wx0*wy1*t10 + wx1*wy1*t11;
      simv[(size_t)(k*8 + ch)*HW] = s;
    }
  } else {
    // ---- exact fallback: per lane, 6 depths, full 32-channel dots ----
    const float* tff  = tf + (size_t)(v+1)*HW*C_;
    const float* refp = tf + (size_t)p*C_;
    const int ZE = (4-v)*HW*C_;     // element offset of zero pad
    #pragma unroll 1
    for (int k = 0; k < 6; ++k) {
      float dep = dpk[k];
      float Z  = rz*dep + t2;
      float px = (rx*dep + t0) / Z;
      float py = (ry*dep + t1) / Z;
      float x0f = floorf(px), y0f = floorf(py);
      float wx1 = px - x0f, wy1 = py - y0f;
      float wx0 = 1.0f - wx1, wy0 = 1.0f - wy1;
      int x0 = (int)x0f, y0 = (int)y0f;
      int x1 = x0 + 1,   y1 = y0 + 1;
      bool vx0 = ((unsigned)x0 <= (unsigned)(W_-1));
      bool vx1 = ((unsigned)x1 <= (unsigned)(W_-1));
      bool vy0 = ((unsigned)y0 <= (unsigned)(H_-1));
      bool vy1 = ((unsigned)y1 <= (unsigned)(H_-1));
      int cx0 = min(max(x0, 0), W_-1);
      int cx1 = min(max(x1, 0), W_-1);
      int cy0 = min(max(y0, 0), H_-1);
      int cy1 = min(max(y1, 0), H_-1);
      int o00 = (vx0 && vy0) ? (cy0*W_+cx0)*C_ : ZE;
      int o01 = (vx1 && vy0) ? (cy0*W_+cx1)*C_ : ZE;
      int o10 = (vx0 && vy1) ? (cy1*W_+cx0)*C_ : ZE;
      int o11 = (vx1 && vy1) ? (cy1*W_+cx1)*C_ : ZE;
      float a00=0.f, a01=0.f, a10=0.f, a11=0.f;
      #pragma unroll 1
      for (int q = 0; q < 8; ++q) {
        float4 rq = *(const float4*)(refp + q*4);
        float4 c0 = *(const float4*)(tff + o00 + q*4);
        float4 c1 = *(const float4*)(tff + o01 + q*4);
        float4 c2 = *(const float4*)(tff + o10 + q*4);
        float4 c3 = *(const float4*)(tff + o11 + q*4);
        a00 += c0.x*rq.x + c0.y*rq.y + c0.z*rq.z + c0.w*rq.w;
        a01 += c1.x*rq.x + c1.y*rq.y + c1.z*rq.z + c1.w*rq.w;
        a10 += c2.x*rq.x + c2.y*rq.y + c2.z*rq.z + c2.w*rq.w;
        a11 += c3.x*rq.x + c3.y*rq.y + c3.z*rq.z + c3.w*rq.w;
      }
      float s = (wx0*wy0*a00 + wx1*wy0*a01 + wx0*wy1*a10 + wx1*wy1*a11)
                * (1.0f/(float)C_);
      simv[(size_t)(k*8 + ch)*HW] = s;
    }
  }
}

// ---------------- MLP: 4 depths per thread, atomic-max logit -------------
__global__ void __launch_bounds__(256)
k_mlp(const float* __restrict__ sim_all,
      const float* __restrict__ w0, const float* __restrict__ b0,
      const float* __restrict__ w1, const float* __restrict__ b1,
      const float* __restrict__ w2, const float* __restrict__ b2,
      unsigned* __restrict__ vwu) {
  int idx = blockIdx.x*blockDim.x + threadIdx.x;
  if (idx >= NV*(D_/4)*HW) return;
  int p = idx % HW;
  int t = idx / HW;           // (v, chunk)
  int v = t / (D_/4);
  int c = t % (D_/4);

  const float* sp_ = sim_all + ((size_t)(v*D_ + c*4))*HW + p;
  float sv[4];
  sv[0] = sp_[0];
  sv[1] = sp_[HW];
  sv[2] = sp_[2*HW];
  sv[3] = sp_[3*HW];

  float ymax = -3.0e38f;
  #pragma unroll
  for (int k = 0; k < 4; ++k) {
    float s = sv[k];
    float acc0 = b1[0], acc1 = b1[1], acc2 = b1[2], acc3 = b1[3];
    float acc4 = b1[4], acc5 = b1[5], acc6 = b1[6], acc7 = b1[7];
    #pragma unroll
    for (int o = 0; o < 16; ++o) {
      float h = fmaxf(fmaf(w0[o], s, b0[o]), 0.0f);
      acc0 = fmaf(w1[0*16+o], h, acc0);
      acc1 = fmaf(w1[1*16+o], h, acc1);
      acc2 = fmaf(w1[2*16+o], h, acc2);
      acc3 = fmaf(w1[3*16+o], h, acc3);
      acc4 = fmaf(w1[4*16+o], h, acc4);
      acc5 = fmaf(w1[5*16+o], h, acc5);
      acc6 = fmaf(w1[6*16+o], h, acc6);
      acc7 = fmaf(w1[7*16+o], h, acc7);
    }
    float yv = b2[0];
    yv = fmaf(w2[0], fmaxf(acc0, 0.0f), yv);
    yv = fmaf(w2[1], fmaxf(acc1, 0.0f), yv);
    yv = fmaf(w2[2], fmaxf(acc2, 0.0f), yv);
    yv = fmaf(w2[3], fmaxf(acc3, 0.0f), yv);
    yv = fmaf(w2[4], fmaxf(acc4, 0.0f), yv);
    yv = fmaf(w2[5], fmaxf(acc5, 0.0f), yv);
    yv = fmaf(w2[6], fmaxf(acc6, 0.0f), yv);
    yv = fmaf(w2[7], fmaxf(acc7, 0.0f), yv);
    ymax = fmaxf(ymax, yv);
  }
  atomicMax(&vwu[(size_t)v*HW + p], ordf(ymax));
}

// ---------------- fused: vw-decode + fuse + conv + softmax/argmax ----------
__global__ void __launch_bounds__(256)
k_fct(const float* __restrict__ sim_all, const unsigned* __restrict__ vwu,
      const float* __restrict__ rw, const float* __restrict__ rb,
      const float* __restrict__ dv, float* __restrict__ out) {
  __shared__ float sfus[D_][TYH][TXH+1];
  __shared__ float scost[D_][64];
  __shared__ float svw[NV][NCOL];
  __shared__ float sinvw[NCOL];
  __shared__ int   sgpc[NCOL];

  int tid = threadIdx.x;
  int gx0 = blockIdx.x*TX;
  int gy0 = blockIdx.y*TY;

  // phase A: per-column view weights (decode + sigmoid) / inv wsum / pixel idx
  if (tid < NCOL) {
    int yy = tid / TXH, xx = tid % TXH;
    int gy = gy0 + yy - 1, gx = gx0 + xx - 1;
    bool valid = (gx >= 0) && (gx < W_) && (gy >= 0) && (gy < H_);
    int gp = min(max(gy,0),H_-1)*W_ + min(max(gx,0),W_-1);
    sgpc[tid] = gp;
    float a0 = 1.0f/(1.0f + expf(-deordf(vwu[0*HW+gp])));
    float a1 = 1.0f/(1.0f + expf(-deordf(vwu[1*HW+gp])));
    float a2 = 1.0f/(1.0f + expf(-deordf(vwu[2*HW+gp])));
    float a3 = 1.0f/(1.0f + expf(-deordf(vwu[3*HW+gp])));
    float inv = valid ? 1.0f/(1e-5f + a0+a1+a2+a3) : 0.0f;
    if (!valid) { a0=a1=a2=a3=0.f; }
    svw[0][tid]=a0; svw[1][tid]=a1; svw[2][tid]=a2; svw[3][tid]=a3;
    sinvw[tid] = inv;
  }
  __syncthreads();

  // phase B: fill fused volume tile (invalid columns auto-zero via weights)
  for (int j = tid; j < D_*NCOL; j += 256) {
    int d = j / NCOL, r = j % NCOL;
    int gp = sgpc[r];
    float s0 = sim_all[(size_t)(0*D_+d)*HW + gp];
    float s1 = sim_all[(size_t)(1*D_+d)*HW + gp];
    float s2 = sim_all[(size_t)(2*D_+d)*HW + gp];
    float s3 = sim_all[(size_t)(3*D_+d)*HW + gp];
    float val = (s0*svw[0][r] + s1*svw[1][r] + s2*svw[2][r] + s3*svw[3][r]) * sinvw[r];
    int yy = r / TXH, xx = r % TXH;
    sfus[d][yy][xx] = val;
  }
  __syncthreads();

  // phase C: 3x3x3 conv; thread = (pixel, depth-group of 12)
  {
    int pid = tid & 63;
    int dg  = tid >> 6;
    int px = pid & 15, py = pid >> 4;
    float kw[27];
    #pragma unroll
    for (int i = 0; i < 27; ++i) kw[i] = rw[i];
    float bias = rb[0];

    float pm1[9], p0[9], pp1[9];
    int d0 = dg*12;
    #pragma unroll
    for (int i = 0; i < 9; ++i) {
      int ky = i/3, kx = i%3;
      pm1[i] = (d0 > 0) ? sfus[d0-1][py+ky][px+kx] : 0.0f;
      p0[i]  = sfus[d0][py+ky][px+kx];
    }
    #pragma unroll
    for (int k = 0; k < 12; ++k) {
      int d = d0 + k;
      #pragma unroll
      for (int i = 0; i < 9; ++i) {
        int ky = i/3, kx = i%3;
        pp1[i] = (d+1 < D_) ? sfus[d+1][py+ky][px+kx] : 0.0f;
      }
      float acc = bias;
      #pragma unroll
      for (int i = 0; i < 9; ++i) acc += pm1[i]*kw[i];
      #pragma unroll
      for (int i = 0; i < 9; ++i) acc += p0[i]*kw[9+i];
      #pragma unroll
      for (int i = 0; i < 9; ++i) acc += pp1[i]*kw[18+i];
      scost[d][pid] = acc;
      #pragma unroll
      for (int i = 0; i < 9; ++i) { pm1[i] = p0[i]; p0[i] = pp1[i]; }
    }
  }
  __syncthreads();

  // phase D: softmax / argmax / outputs, one thread per pixel (single exp pass)
  if (tid < 64) {
    int tx = tid & 15, ty = tid >> 4;
    int gx = gx0 + tx, gy = gy0 + ty;
    int gp = gy*W_ + gx;
    float vmax = scost[0][tid];
    int am = 0;
    #pragma unroll
    for (int d = 1; d < D_; ++d) {
      float c = scost[d][tid];
      if (c > vmax) { vmax = c; am = d; }
    }
    float sum = 0.0f;
    #pragma unroll
    for (int d = 0; d < D_; ++d) {
      float e = expf(scost[d][tid] - vmax);
      scost[d][tid] = e;         // each thread owns column tid
      sum += e;
    }
    float inv = 1.0f / sum;
    #pragma unroll
    for (int d = 0; d < D_; ++d)
      out[(size_t)(2*HW) + (size_t)d*HW + gp] = scost[d][tid] * inv;
    out[gp] = dv[(size_t)am*HW + gp];
    out[HW + gp] = inv;
    // view_weights output
    int rint = (ty+1)*TXH + (tx+1);
    #pragma unroll
    for (int v = 0; v < NV; ++v)
      out[(size_t)(2*HW + D_*HW) + (size_t)v*HW + gp] = svw[v][rint];
  }
}

// ---------------- launch ----------------
extern "C" void kernel_launch(void* const* d_in, const int* in_sizes, int n_in,
                              void* d_out, int out_size, void* d_ws, size_t ws_size,
                              hipStream_t stream) {
  const float* feat = (const float*)d_in[0];
  const float* pm   = (const float*)d_in[1];
  const float* dv   = (const float*)d_in[2];
  const float* w0   = (const float*)d_in[3];
  const float* b0   = (const float*)d_in[4];
  const float* w1   = (const float*)d_in[5];
  const float* b1   = (const float*)d_in[6];
  const float* w2   = (const float*)d_in[7];
  const float* b2   = (const float*)d_in[8];
  const float* rw   = (const float*)d_in[9];
  const float* rb   = (const float*)d_in[10];
  float* out = (float*)d_out;
  float* ws  = (float*)d_ws;

  // workspace layout (floats)
  float*    xf  = ws;                        // 48 (pad 64)
  float*    tf  = ws + 64;                   // 5*HW*C + 64 zero-pad
  float*    sim = ws + 3276928;              // 4*48*HW = 3,932,160
  unsigned* vwu = (unsigned*)(ws + 7209088); // 4*HW = 81,920
  // high-water mark: ~7.29M floats = ~27.9 MB

  hipLaunchKernelGGL(k_prep, dim3(HW/64, 5), dim3(256), 0, stream,
                     feat, pm, tf, xf, vwu);
  hipLaunchKernelGGL(k_warp, dim3((NV*HW*8)/256), dim3(256), 0, stream,
                     tf, dv, xf, sim);
  hipLaunchKernelGGL(k_mlp, dim3((NV*(D_/4)*HW)/256), dim3(256), 0, stream,
                     sim, w0, b0, w1, b1, w2, b2, vwu);
  hipLaunchKernelGGL(k_fct, dim3(W_/TX, H_/TY), dim3(256), 0, stream,
                     sim, vwu, rw, rb, dv, out);
}